// Round 6
// baseline (199.305 us; speedup 1.0000x reference)
//
#include <hip/hip_runtime.h>
#include <hip/hip_bf16.h>

#define BDIM   256
#define BATCH  32
#define CH     128
#define NLEN   65536
#define NV4    (NLEN / 4)      // 16384 float4 per row
#define KSEL   6553            // int(65536 * 0.1)
#define VPT    4               // float4 per thread (kernel 1)
#define HISTB  4096

typedef float v4f __attribute__((ext_vector_type(4)));

// ---------------------------------------------------------------------------
// Kernel 1: scores[b,n] = |sum_c x[b,c,n]*W[c] + bias|   (memory-bound, 1 GiB)
// Contiguous per-c load windows (4 x 1KB wave-loads per c, 16 in flight),
// nontemporal streaming of x. When FUSED, also builds the level-1 radix
// histogram (bits 30..19 of |score| bits) for its row: LDS hist over the
// block's 4096 elements, then nonzero bins atomicAdd'd to ghist[row][4096].
// This rides free under the BW-bound loop (>90% VALU slack).
// ---------------------------------------------------------------------------
template <bool FUSED>
__global__ __launch_bounds__(BDIM) void conv_score_kernel(
    const float* __restrict__ x, const float* __restrict__ W,
    const float* __restrict__ bias, float* __restrict__ scores,
    int* __restrict__ ghist) {
  __shared__ float sW[CH];
  __shared__ int   lhist[HISTB];
  if (threadIdx.x < CH) sW[threadIdx.x] = W[threadIdx.x];
  if (FUSED) {
#pragma unroll
    for (int j = 0; j < HISTB / (BDIM * 4); ++j)   // 4096 ints = 1024 int4
      ((int4*)lhist)[threadIdx.x + j * BDIM] = make_int4(0, 0, 0, 0);
  }
  __syncthreads();

  const size_t blockStart = (size_t)blockIdx.x * (BDIM * VPT); // float4 units
  const int    row        = (int)(blockStart >> 14);           // / NV4
  const size_t nbase      = blockStart & (NV4 - 1);

  const v4f* xp = (const v4f*)x + (size_t)row * CH * NV4 + nbase
                  + threadIdx.x;

  v4f acc[VPT];
#pragma unroll
  for (int i = 0; i < VPT; ++i) acc[i] = (v4f)0.f;

#pragma unroll 4
  for (int c = 0; c < CH; ++c) {
    const v4f* p = xp + (size_t)c * NV4;
    float w = sW[c];
#pragma unroll
    for (int i = 0; i < VPT; ++i) {
      v4f v = __builtin_nontemporal_load(p + i * BDIM);
      acc[i].x = fmaf(v.x, w, acc[i].x);
      acc[i].y = fmaf(v.y, w, acc[i].y);
      acc[i].z = fmaf(v.z, w, acc[i].z);
      acc[i].w = fmaf(v.w, w, acc[i].w);
    }
  }

  float bb = bias[0];
  v4f* op = (v4f*)scores + blockStart + threadIdx.x;
#pragma unroll
  for (int i = 0; i < VPT; ++i) {
    v4f r;
    r.x = fabsf(acc[i].x + bb);
    r.y = fabsf(acc[i].y + bb);
    r.z = fabsf(acc[i].z + bb);
    r.w = fabsf(acc[i].w + bb);
    op[i * BDIM] = r;
    if (FUSED) {
      atomicAdd(&lhist[__float_as_uint(r.x) >> 19], 1);
      atomicAdd(&lhist[__float_as_uint(r.y) >> 19], 1);
      atomicAdd(&lhist[__float_as_uint(r.z) >> 19], 1);
      atomicAdd(&lhist[__float_as_uint(r.w) >> 19], 1);
    }
  }

  if (FUSED) {
    __syncthreads();
    int* gh = ghist + (size_t)row * HISTB;
#pragma unroll
    for (int j = 0; j < HISTB / BDIM; ++j) {
      int bin = threadIdx.x + j * BDIM;   // coalesced across the wave
      int c = lhist[bin];
      if (c) atomicAdd(&gh[bin], c);
    }
  }
}

// ---------------------------------------------------------------------------
// Kernel 2: exact top-k mean per row via 3-level radix select on float bits.
// Nonnegative floats compare identically as uint32, so radix-select on the
// bit pattern is exact (including ties: all equal bits == equal values).
// ---------------------------------------------------------------------------
__device__ __forceinline__ int waveReduceI(int v) {
#pragma unroll
  for (int o = 32; o > 0; o >>= 1) v += __shfl_down(v, o);
  return v;
}
__device__ __forceinline__ float waveReduceF(float v) {
#pragma unroll
  for (int o = 32; o > 0; o >>= 1) v += __shfl_down(v, o);
  return v;
}

// Parallel bucket-select over hist[4096] (LDS or global), descending bucket
// order. Thread t owns 4 descending buckets {4095-4t-j}. Exclusive prefix via
// wave shfl_up scan + per-wave totals; the unique crossing thread writes
// ctrl[0]=bucket, ctrl[1]=remaining need inside it.
__device__ void findBucket(const int* hist, int* waveSum, int* ctrl,
                           int need, int tid, int lane, int w) {
  int c0 = hist[4095 - 4 * tid];
  int c1 = hist[4094 - 4 * tid];
  int c2 = hist[4093 - 4 * tid];
  int c3 = hist[4092 - 4 * tid];
  int part = c0 + c1 + c2 + c3;

  int inc = part;
#pragma unroll
  for (int o = 1; o <= 32; o <<= 1) {
    int t = __shfl_up(inc, o);
    if (lane >= o) inc += t;
  }
  if (lane == 63) waveSum[w] = inc;
  __syncthreads();

  int waveBase = 0;
#pragma unroll
  for (int i = 0; i < 16; ++i) waveBase += (i < w) ? waveSum[i] : 0;

  int excl = waveBase + inc - part;  // count in buckets above this group
  if (excl < need && excl + part >= need) {
    int cum = excl, T, rem;
    if (cum + c0 >= need)              { T = 4095 - 4 * tid; rem = need - cum; }
    else if ((cum += c0) + c1 >= need) { T = 4094 - 4 * tid; rem = need - cum; }
    else if ((cum += c1) + c2 >= need) { T = 4093 - 4 * tid; rem = need - cum; }
    else { cum += c2;                    T = 4092 - 4 * tid; rem = need - cum; }
    ctrl[0] = T;
    ctrl[1] = rem;
  }
  __syncthreads();
}

template <bool FUSED>
__global__ __launch_bounds__(1024) void topk_mean_kernel(
    const float* __restrict__ scores, const int* __restrict__ ghist,
    float* __restrict__ out) {
  __shared__ int   hist[HISTB];
  __shared__ int   waveSum[16];
  __shared__ float fws[16];
  __shared__ int   ctrl[2];

  const int tid  = threadIdx.x;
  const int lane = tid & 63;
  const int w    = tid >> 6;
  const int row  = blockIdx.x;
  const float4* sp = (const float4*)(scores + (size_t)row * NLEN);

  // Cache the whole row in registers: 16 x uint4 = 64 VGPRs.
  uint4 uv[16];
#pragma unroll
  for (int i = 0; i < 16; ++i) {
    float4 v = sp[i * 1024 + tid];
    uv[i].x = __float_as_uint(v.x);
    uv[i].y = __float_as_uint(v.y);
    uv[i].z = __float_as_uint(v.z);
    uv[i].w = __float_as_uint(v.w);
  }

  // ---- level 1: bits 30..19. FUSED: precomputed by conv kernel.
  if (FUSED) {
    findBucket(ghist + (size_t)row * HISTB, waveSum, ctrl, KSEL, tid, lane, w);
  } else {
    ((uint4*)hist)[tid] = make_uint4(0, 0, 0, 0);
    __syncthreads();
#pragma unroll
    for (int i = 0; i < 16; ++i) {
      atomicAdd(&hist[uv[i].x >> 19], 1);
      atomicAdd(&hist[uv[i].y >> 19], 1);
      atomicAdd(&hist[uv[i].z >> 19], 1);
      atomicAdd(&hist[uv[i].w >> 19], 1);
    }
    __syncthreads();
    findBucket(hist, waveSum, ctrl, KSEL, tid, lane, w);
  }
  const unsigned T1    = (unsigned)ctrl[0];
  const int      need1 = ctrl[1];

  // ---- level 2: bits 18..7 among elements whose top bits == T1
  ((uint4*)hist)[tid] = make_uint4(0, 0, 0, 0);
  __syncthreads();
#pragma unroll
  for (int i = 0; i < 16; ++i) {
    unsigned a;
    a = uv[i].x; if ((a >> 19) == T1) atomicAdd(&hist[(a >> 7) & 4095], 1);
    a = uv[i].y; if ((a >> 19) == T1) atomicAdd(&hist[(a >> 7) & 4095], 1);
    a = uv[i].z; if ((a >> 19) == T1) atomicAdd(&hist[(a >> 7) & 4095], 1);
    a = uv[i].w; if ((a >> 19) == T1) atomicAdd(&hist[(a >> 7) & 4095], 1);
  }
  __syncthreads();
  findBucket(hist, waveSum, ctrl, need1, tid, lane, w);
  const unsigned prefix23 = (T1 << 12) | (unsigned)ctrl[0];  // == u >> 7
  const int      need2    = ctrl[1];

  // ---- level 3: bits 6..0 among elements whose (u >> 7) == prefix23
  ((uint4*)hist)[tid] = make_uint4(0, 0, 0, 0);
  __syncthreads();
#pragma unroll
  for (int i = 0; i < 16; ++i) {
    unsigned a;
    a = uv[i].x; if ((a >> 7) == prefix23) atomicAdd(&hist[a & 127], 1);
    a = uv[i].y; if ((a >> 7) == prefix23) atomicAdd(&hist[a & 127], 1);
    a = uv[i].z; if ((a >> 7) == prefix23) atomicAdd(&hist[a & 127], 1);
    a = uv[i].w; if ((a >> 7) == prefix23) atomicAdd(&hist[a & 127], 1);
  }
  __syncthreads();
  findBucket(hist, waveSum, ctrl, need2, tid, lane, w);
  const unsigned vstar = (prefix23 << 7) | (unsigned)ctrl[0];  // k-th largest

  // ---- final: sum of strictly-greater + ties at vstar, then mean
  float sGt = 0.f;
  int   cGt = 0;
#pragma unroll
  for (int i = 0; i < 16; ++i) {
    unsigned a;
    a = uv[i].x; if (a > vstar) { sGt += __uint_as_float(a); ++cGt; }
    a = uv[i].y; if (a > vstar) { sGt += __uint_as_float(a); ++cGt; }
    a = uv[i].z; if (a > vstar) { sGt += __uint_as_float(a); ++cGt; }
    a = uv[i].w; if (a > vstar) { sGt += __uint_as_float(a); ++cGt; }
  }
  sGt = waveReduceF(sGt);
  cGt = waveReduceI(cGt);
  if (lane == 0) { fws[w] = sGt; waveSum[w] = cGt; }
  __syncthreads();
  if (tid == 0) {
    float s = 0.f;
    int   c = 0;
    for (int i = 0; i < 16; ++i) { s += fws[i]; c += waveSum[i]; }
    float total = s + (float)(KSEL - c) * __uint_as_float(vstar);
    out[row] = total / (float)KSEL;
  }
}

// ---------------------------------------------------------------------------
extern "C" void kernel_launch(void* const* d_in, const int* in_sizes, int n_in,
                              void* d_out, int out_size, void* d_ws, size_t ws_size,
                              hipStream_t stream) {
  const float* x    = (const float*)d_in[0];
  const float* W    = (const float*)d_in[1];
  const float* bias = (const float*)d_in[2];
  float* out    = (float*)d_out;
  float* scores = (float*)d_ws;  // B*N floats = 8 MB

  const size_t scoresBytes = (size_t)BATCH * NLEN * sizeof(float);
  const size_t histBytes   = (size_t)BATCH * HISTB * sizeof(int);
  int* ghist = (int*)((char*)d_ws + scoresBytes);
  const bool fused = ws_size >= scoresBytes + histBytes;

  int blocks1 = (BATCH * NV4) / (BDIM * VPT);  // 512
  if (fused) {
    hipMemsetAsync(ghist, 0, histBytes, stream);
    conv_score_kernel<true><<<blocks1, BDIM, 0, stream>>>(x, W, bias, scores, ghist);
    topk_mean_kernel<true><<<BATCH, 1024, 0, stream>>>(scores, ghist, out);
  } else {
    conv_score_kernel<false><<<blocks1, BDIM, 0, stream>>>(x, W, bias, scores, ghist);
    topk_mean_kernel<false><<<BATCH, 1024, 0, stream>>>(scores, ghist, out);
  }
}

// Round 7
// 196.369 us; speedup vs baseline: 1.0150x; 1.0150x over previous
//
#include <hip/hip_runtime.h>
#include <hip/hip_bf16.h>

#define BDIM   256
#define BATCH  32
#define CH     128
#define NLEN   65536
#define NV4    (NLEN / 4)      // 16384 float4 per row
#define KSEL   6553            // int(65536 * 0.1)
#define VPT    4               // float4 per thread (kernel 1)
#define HISTB  4096
#define SEGS   8               // histogram sub-blocks per row (kernel 2A)

typedef float v4f __attribute__((ext_vector_type(4)));

// ---------------------------------------------------------------------------
// Kernel 1: scores[b,n] = |sum_c x[b,c,n]*W[c] + bias|   (memory-bound, 1 GiB)
// Contiguous per-c load windows (4 x 1KB wave-loads per c, 16 in flight),
// nontemporal streaming of x. Identical to the round-4 best (193.3 us).
// ---------------------------------------------------------------------------
__global__ __launch_bounds__(BDIM) void conv_score_kernel(
    const float* __restrict__ x, const float* __restrict__ W,
    const float* __restrict__ bias, float* __restrict__ scores) {
  __shared__ float sW[CH];
  if (threadIdx.x < CH) sW[threadIdx.x] = W[threadIdx.x];
  __syncthreads();

  const size_t blockStart = (size_t)blockIdx.x * (BDIM * VPT); // float4 units
  const int    row        = (int)(blockStart >> 14);           // / NV4
  const size_t nbase      = blockStart & (NV4 - 1);

  const v4f* xp = (const v4f*)x + (size_t)row * CH * NV4 + nbase
                  + threadIdx.x;

  v4f acc[VPT];
#pragma unroll
  for (int i = 0; i < VPT; ++i) acc[i] = (v4f)0.f;

#pragma unroll 4
  for (int c = 0; c < CH; ++c) {
    const v4f* p = xp + (size_t)c * NV4;
    float w = sW[c];
#pragma unroll
    for (int i = 0; i < VPT; ++i) {
      v4f v = __builtin_nontemporal_load(p + i * BDIM);
      acc[i].x = fmaf(v.x, w, acc[i].x);
      acc[i].y = fmaf(v.y, w, acc[i].y);
      acc[i].z = fmaf(v.z, w, acc[i].z);
      acc[i].w = fmaf(v.w, w, acc[i].w);
    }
  }

  float bb = bias[0];
  v4f* op = (v4f*)scores + blockStart + threadIdx.x;
#pragma unroll
  for (int i = 0; i < VPT; ++i) {
    v4f r;
    r.x = fabsf(acc[i].x + bb);
    r.y = fabsf(acc[i].y + bb);
    r.z = fabsf(acc[i].z + bb);
    r.w = fabsf(acc[i].w + bb);
    op[i * BDIM] = r;
  }
}

// ---------------------------------------------------------------------------
// Kernel 2A: per-segment level-1 histograms. 8 blocks per row, each builds a
// private 4096-bin LDS histogram of bits 30..19 over 8192 elements, then
// stores it (plain coalesced stores, no atomics, fully overwritten every
// call) to phist[blockIdx][4096]. 8x less atomic serialization per block and
// 8x more CUs than doing level 1 inside the 32-block select kernel.
// ---------------------------------------------------------------------------
__global__ __launch_bounds__(256) void hist_kernel(
    const float* __restrict__ scores, int* __restrict__ phist) {
  __shared__ int lhist[HISTB];
#pragma unroll
  for (int j = 0; j < HISTB / (256 * 4); ++j)
    ((int4*)lhist)[threadIdx.x + j * 256] = make_int4(0, 0, 0, 0);
  __syncthreads();

  const int row = blockIdx.x >> 3;
  const int seg = blockIdx.x & (SEGS - 1);
  const uint4* sp = (const uint4*)(scores + (size_t)row * NLEN
                                   + (size_t)seg * (NLEN / SEGS));
#pragma unroll
  for (int i = 0; i < (NLEN / SEGS) / (256 * 4); ++i) {   // 8 iters
    uint4 v = sp[threadIdx.x + i * 256];
    atomicAdd(&lhist[v.x >> 19], 1);
    atomicAdd(&lhist[v.y >> 19], 1);
    atomicAdd(&lhist[v.z >> 19], 1);
    atomicAdd(&lhist[v.w >> 19], 1);
  }
  __syncthreads();

  int4* outp = (int4*)(phist + (size_t)blockIdx.x * HISTB);
#pragma unroll
  for (int j = 0; j < HISTB / (256 * 4); ++j)
    outp[threadIdx.x + j * 256] = ((int4*)lhist)[threadIdx.x + j * 256];
}

// ---------------------------------------------------------------------------
// Kernel 2B: exact top-k mean per row via 3-level radix select on float bits.
// Nonnegative floats compare identically as uint32, so radix-select on the
// bit pattern is exact (including ties: all equal bits == equal values).
// ---------------------------------------------------------------------------
__device__ __forceinline__ int waveReduceI(int v) {
#pragma unroll
  for (int o = 32; o > 0; o >>= 1) v += __shfl_down(v, o);
  return v;
}
__device__ __forceinline__ float waveReduceF(float v) {
#pragma unroll
  for (int o = 32; o > 0; o >>= 1) v += __shfl_down(v, o);
  return v;
}

// Parallel bucket-select, descending bucket order; thread t owns buckets
// {4095-4t (c0), 4094-4t (c1), 4093-4t (c2), 4092-4t (c3)}. Exclusive prefix
// via wave shfl_up scan + per-wave totals; the unique crossing thread writes
// ctrl[0]=bucket, ctrl[1]=remaining need inside it.
__device__ void findBucketC(int c0, int c1, int c2, int c3,
                            int* waveSum, int* ctrl,
                            int need, int tid, int lane, int w) {
  int part = c0 + c1 + c2 + c3;

  int inc = part;
#pragma unroll
  for (int o = 1; o <= 32; o <<= 1) {
    int t = __shfl_up(inc, o);
    if (lane >= o) inc += t;
  }
  if (lane == 63) waveSum[w] = inc;
  __syncthreads();

  int waveBase = 0;
#pragma unroll
  for (int i = 0; i < 16; ++i) waveBase += (i < w) ? waveSum[i] : 0;

  int excl = waveBase + inc - part;  // count in buckets above this group
  if (excl < need && excl + part >= need) {
    int cum = excl, T, rem;
    if (cum + c0 >= need)              { T = 4095 - 4 * tid; rem = need - cum; }
    else if ((cum += c0) + c1 >= need) { T = 4094 - 4 * tid; rem = need - cum; }
    else if ((cum += c1) + c2 >= need) { T = 4093 - 4 * tid; rem = need - cum; }
    else { cum += c2;                    T = 4092 - 4 * tid; rem = need - cum; }
    ctrl[0] = T;
    ctrl[1] = rem;
  }
  __syncthreads();
}

__device__ void findBucket(const int* hist, int* waveSum, int* ctrl,
                           int need, int tid, int lane, int w) {
  findBucketC(hist[4095 - 4 * tid], hist[4094 - 4 * tid],
              hist[4093 - 4 * tid], hist[4092 - 4 * tid],
              waveSum, ctrl, need, tid, lane, w);
}

__global__ __launch_bounds__(1024) void topk_mean_kernel(
    const float* __restrict__ scores, const int* __restrict__ phist,
    float* __restrict__ out) {
  __shared__ int   hist[HISTB];
  __shared__ int   waveSum[16];
  __shared__ float fws[16];
  __shared__ int   ctrl[2];

  const int tid  = threadIdx.x;
  const int lane = tid & 63;
  const int w    = tid >> 6;
  const int row  = blockIdx.x;
  const float4* sp = (const float4*)(scores + (size_t)row * NLEN);

  // Cache the whole row in registers: 16 x uint4 = 64 VGPRs.
  uint4 uv[16];
#pragma unroll
  for (int i = 0; i < 16; ++i) {
    float4 v = sp[i * 1024 + tid];
    uv[i].x = __float_as_uint(v.x);
    uv[i].y = __float_as_uint(v.y);
    uv[i].z = __float_as_uint(v.z);
    uv[i].w = __float_as_uint(v.w);
  }

  // ---- level 1: bits 30..19, from the precomputed partial histograms.
  // int4 at index (1023-tid) of each partial = bins {4092-4t,...,4095-4t}
  // = {c3, c2, c1, c0}.
  {
    const int4* ph = (const int4*)(phist + (size_t)row * SEGS * HISTB);
    int4 s = make_int4(0, 0, 0, 0);
#pragma unroll
    for (int p = 0; p < SEGS; ++p) {
      int4 h = ph[p * (HISTB / 4) + (1023 - tid)];
      s.x += h.x; s.y += h.y; s.z += h.z; s.w += h.w;
    }
    findBucketC(s.w, s.z, s.y, s.x, waveSum, ctrl, KSEL, tid, lane, w);
  }
  const unsigned T1    = (unsigned)ctrl[0];
  const int      need1 = ctrl[1];

  // ---- level 2: bits 18..7 among elements whose top bits == T1
  ((uint4*)hist)[tid] = make_uint4(0, 0, 0, 0);
  __syncthreads();
#pragma unroll
  for (int i = 0; i < 16; ++i) {
    unsigned a;
    a = uv[i].x; if ((a >> 19) == T1) atomicAdd(&hist[(a >> 7) & 4095], 1);
    a = uv[i].y; if ((a >> 19) == T1) atomicAdd(&hist[(a >> 7) & 4095], 1);
    a = uv[i].z; if ((a >> 19) == T1) atomicAdd(&hist[(a >> 7) & 4095], 1);
    a = uv[i].w; if ((a >> 19) == T1) atomicAdd(&hist[(a >> 7) & 4095], 1);
  }
  __syncthreads();
  findBucket(hist, waveSum, ctrl, need1, tid, lane, w);
  const unsigned prefix23 = (T1 << 12) | (unsigned)ctrl[0];  // == u >> 7
  const int      need2    = ctrl[1];

  // ---- level 3: bits 6..0 among elements whose (u >> 7) == prefix23
  ((uint4*)hist)[tid] = make_uint4(0, 0, 0, 0);
  __syncthreads();
#pragma unroll
  for (int i = 0; i < 16; ++i) {
    unsigned a;
    a = uv[i].x; if ((a >> 7) == prefix23) atomicAdd(&hist[a & 127], 1);
    a = uv[i].y; if ((a >> 7) == prefix23) atomicAdd(&hist[a & 127], 1);
    a = uv[i].z; if ((a >> 7) == prefix23) atomicAdd(&hist[a & 127], 1);
    a = uv[i].w; if ((a >> 7) == prefix23) atomicAdd(&hist[a & 127], 1);
  }
  __syncthreads();
  findBucket(hist, waveSum, ctrl, need2, tid, lane, w);
  const unsigned vstar = (prefix23 << 7) | (unsigned)ctrl[0];  // k-th largest

  // ---- final: sum of strictly-greater + ties at vstar, then mean
  float sGt = 0.f;
  int   cGt = 0;
#pragma unroll
  for (int i = 0; i < 16; ++i) {
    unsigned a;
    a = uv[i].x; if (a > vstar) { sGt += __uint_as_float(a); ++cGt; }
    a = uv[i].y; if (a > vstar) { sGt += __uint_as_float(a); ++cGt; }
    a = uv[i].z; if (a > vstar) { sGt += __uint_as_float(a); ++cGt; }
    a = uv[i].w; if (a > vstar) { sGt += __uint_as_float(a); ++cGt; }
  }
  sGt = waveReduceF(sGt);
  cGt = waveReduceI(cGt);
  if (lane == 0) { fws[w] = sGt; waveSum[w] = cGt; }
  __syncthreads();
  if (tid == 0) {
    float s = 0.f;
    int   c = 0;
    for (int i = 0; i < 16; ++i) { s += fws[i]; c += waveSum[i]; }
    float total = s + (float)(KSEL - c) * __uint_as_float(vstar);
    out[row] = total / (float)KSEL;
  }
}

// ---------------------------------------------------------------------------
extern "C" void kernel_launch(void* const* d_in, const int* in_sizes, int n_in,
                              void* d_out, int out_size, void* d_ws, size_t ws_size,
                              hipStream_t stream) {
  const float* x    = (const float*)d_in[0];
  const float* W    = (const float*)d_in[1];
  const float* bias = (const float*)d_in[2];
  float* out    = (float*)d_out;
  float* scores = (float*)d_ws;  // B*N floats = 8 MB

  const size_t scoresBytes = (size_t)BATCH * NLEN * sizeof(float);
  int* phist = (int*)((char*)d_ws + scoresBytes);   // 256*4096 ints = 4 MB

  int blocks1 = (BATCH * NV4) / (BDIM * VPT);  // 512
  conv_score_kernel<<<blocks1, BDIM, 0, stream>>>(x, W, bias, scores);
  hist_kernel<<<BATCH * SEGS, 256, 0, stream>>>(scores, phist);
  topk_mean_kernel<<<BATCH, 1024, 0, stream>>>(scores, phist, out);
}